// Round 21
// baseline (95.147 us; speedup 1.0000x reference)
//
#include <hip/hip_runtime.h>
#include <math.h>

#define BB 8
#define CC 32
#define TT 9
#define LL 512
#define HH 8
#define DD 4
#define NBT (BB*TT)          // 72
#define RELN (2*LL-1)        // 1023
#define RLN2 1.4426950408889634f
#define SMBW 544             // staged bias window width per head

typedef float  f4v  __attribute__((ext_vector_type(4)));
typedef float  f16v __attribute__((ext_vector_type(16)));
typedef int    i4v  __attribute__((ext_vector_type(4)));
typedef short  s8v  __attribute__((ext_vector_type(8)));   // 8 bf16 = 4 VGPRs

#define EXP2(x) __builtin_amdgcn_exp2f(x)   // raw v_exp_f32

__device__ __forceinline__ unsigned cvtpk(float lo, float hi) {
  unsigned u;
  asm("v_cvt_pk_bf16_f32 %0, %1, %2" : "=v"(u) : "v"(lo), "v"(hi));
  return u;
}

// ---------------- fused pre: proj (blocks 0..575) + pl_w transpose (576..831) + bias (832..835)
// K layout: kb2[bt][ch=c>>4][j=512][c16]  (fragment loads -> contiguous 1KB/wave)
// V layout: vt2[bt][j>>4][c=32][j&15]     (fragment loads -> contiguous 1KB/wave)
__global__ __launch_bounds__(256) void pre_kernel(
    const float* __restrict__ x,
    const float* __restrict__ Wq, const float* __restrict__ bq,
    const float* __restrict__ Wk, const float* __restrict__ bk,
    const float* __restrict__ Wv, const float* __restrict__ bv,
    float* __restrict__ qo, short* __restrict__ kbo, short* __restrict__ vt,
    const float* __restrict__ plw, float* __restrict__ plwT,
    const float* __restrict__ rpb, const float* __restrict__ Wl,
    float* __restrict__ mbr) {
  __shared__ float tile[32][33];
  if (blockIdx.x >= 576) {
    int pid = blockIdx.x - 576;
    if (pid < 256) {
      int bx = (pid & 15) * 32, by = (pid >> 4) * 32;
      int tx = threadIdx.x & 31, ty = threadIdx.x >> 5;   // 32x8
      #pragma unroll
      for (int yy = ty; yy < 32; yy += 8)
        tile[yy][tx] = plw[(by + yy)*LL + bx + tx];
      __syncthreads();
      #pragma unroll
      for (int yy = ty; yy < 32; yy += 8)
        plwT[(bx + yy)*LL + by + tx] = tile[tx][yy];
    } else {
      int xx = (pid - 256) * 256 + threadIdx.x;
      if (xx >= RELN) return;
      int idx = 1022 - xx;
      float r[HH];
      #pragma unroll
      for (int h = 0; h < HH; ++h) r[h] = rpb[h*RELN + idx];
      #pragma unroll
      for (int Ho = 0; Ho < HH; ++Ho) {
        float acc = 0.f;
        #pragma unroll
        for (int h = 0; h < HH; ++h) acc += r[h] * Wl[h*HH + Ho];
        mbr[Ho*1024 + xx] = RLN2 * acc;
      }
    }
    return;
  }

  int bid = blockIdx.x;                 // 0..575
  int gidx = (bid % 144) * 256 + threadIdx.x;    // 0..36863
  int l  = gidx & (LL-1);
  int bt = gidx >> 9;
  int b = bt / TT, t = bt - b*TT;
  const int hq = (bid / 144) * 2;       // first head of this quarter

  float xv[CC];
  #pragma unroll
  for (int c = 0; c < CC; ++c)
    xv[c] = x[((b*CC + c)*TT + t)*LL + l];

  // Q (scaled by 0.5*log2e)
  #pragma unroll
  for (int h = hq; h < hq + 2; ++h) {
    float yv[DD];
    #pragma unroll
    for (int d = 0; d < DD; ++d) {
      int co = h*DD + d;
      float acc = bq[co];
      #pragma unroll
      for (int ci = 0; ci < CC; ++ci) acc += xv[ci] * Wq[co*CC + ci];
      yv[d] = acc;
    }
    float n = sqrtf(yv[0]*yv[0] + yv[1]*yv[1] + yv[2]*yv[2] + yv[3]*yv[3]);
    float inv = 0.5f * RLN2 / fmaxf(n, 1e-12f);
    *reinterpret_cast<float4*>(&qo[((size_t)bt*LL + l)*CC + h*DD]) =
        make_float4(yv[0]*inv, yv[1]*inv, yv[2]*inv, yv[3]*inv);
  }
  // K -> bf16 tiled: kb2[bt][hq>>2][l][(hq&3)*4 .. +8)
  {
    unsigned ku[4];
    #pragma unroll
    for (int hh = 0; hh < 2; ++hh) {
      int h = hq + hh;
      float yv[DD];
      #pragma unroll
      for (int d = 0; d < DD; ++d) {
        int co = h*DD + d;
        float acc = bk[co];
        #pragma unroll
        for (int ci = 0; ci < CC; ++ci) acc += xv[ci] * Wk[co*CC + ci];
        yv[d] = acc;
      }
      float n = sqrtf(yv[0]*yv[0] + yv[1]*yv[1] + yv[2]*yv[2] + yv[3]*yv[3]);
      float inv = 1.0f / fmaxf(n, 1e-12f);
      ku[hh*2]   = cvtpk(yv[0]*inv, yv[1]*inv);
      ku[hh*2+1] = cvtpk(yv[2]*inv, yv[3]*inv);
    }
    const int ch = hq >> 2;
    const int c16b = (hq & 3) * 4;
    *reinterpret_cast<uint4*>(kbo + (((size_t)bt*2 + ch)*LL + l)*16 + c16b) =
        make_uint4(ku[0], ku[1], ku[2], ku[3]);
  }
  // V -> bf16 chunk-tiled: vt2[bt][l>>4][c][l&15]
  #pragma unroll
  for (int h = hq; h < hq + 2; ++h) {
    float yv[DD];
    #pragma unroll
    for (int d = 0; d < DD; ++d) {
      int co = h*DD + d;
      float acc = bv[co];
      #pragma unroll
      for (int ci = 0; ci < CC; ++ci) acc += xv[ci] * Wv[co*CC + ci];
      yv[d] = acc;
    }
    float n = sqrtf(yv[0]*yv[0] + yv[1]*yv[1] + yv[2]*yv[2] + yv[3]*yv[3]);
    float inv = 1.0f / fmaxf(n, 1e-12f);
    #pragma unroll
    for (int d = 0; d < DD; ++d) {
      unsigned u = cvtpk(yv[d]*inv, yv[d]*inv);
      int co = h*DD + d;
      reinterpret_cast<unsigned short*>(vt)[
          (((size_t)bt*32 + (l >> 4))*CC + co)*16 + (l & 15)] =
          (unsigned short)(u & 0xffffu);
    }
  }
}

// ---------------- fused attention + Wm (v21: v20 + jp unroll x4 for ILP) ----------
// 1152 blocks x 256 thr. Block = (bt, 32-row i-block). Wave w: ALL 32 i, heads {2w,2w+1}.
// Lane: c32=lane&31, h5=lane>>5. QK: D[j][i]=K·QM+bias, j=(reg&3)+8(reg>>2)+4h5 [m74],
// i=c32. PV: O^T[c][i] = V^T · P^T via cross-half word exchange (2 bpermute per t).
// jp loop unrolled x4 -> 8 independent chains in flight (exp2 runs at 1/4 VALU rate;
// bias ds_reads + exp chain need deep ILP to overlap).
__global__ __launch_bounds__(256, 2) void attn_kernel(
    const float* __restrict__ q, const short* __restrict__ kb,
    const short* __restrict__ vt,
    const float* __restrict__ Wl, const float* __restrict__ Wc,
    const float* __restrict__ mbr,
    const float* __restrict__ Wm, const float* __restrict__ bm,
    float* __restrict__ out, float* __restrict__ xm8) {
  __shared__ float smb[HH][SMBW];   // 17.4 KB staged bias
  __shared__ float xch[3][64][17];  // non-leader partials, padded
  __shared__ float xt[32][33];      // x_att tile [i][c], padded
  __shared__ float sWm[32][33];     // Wm[co][ci], padded
  __shared__ float sbm[32];

  const int wgid = blockIdx.x;
  const int id   = (wgid & 7) * 144 + (wgid >> 3);   // 1152 % 8 == 0 -> bijective
  const int bt   = id >> 4;       // [0,72)
  const int iblk = id & 15;       // 32-row block
  const int b    = bt / TT, t = bt - b*TT;

  const int tid  = threadIdx.x;
  const int w    = __builtin_amdgcn_readfirstlane(tid >> 6);
  const int lane = tid & 63;
  const int c32  = lane & 31;
  const int h5   = lane >> 5;     // 0,1
  const int it   = iblk*32;
  const int Hb   = 2*w;           // wave's 2 heads

  // stage bias window
  {
    const int xbase = 480 - 32*iblk;
    for (int s = tid; s < HH*SMBW; s += 256) {
      int h = s / SMBW, sx = s - h*SMBW;
      smb[h][sx] = mbr[h*1024 + xbase + sx];
    }
  }
  // preload Wm/bm -> LDS
  {
    int c4 = tid * 4;
    int co = c4 >> 5, ci = c4 & 31;
    float4 wv = *reinterpret_cast<const float4*>(Wm + co*CC + ci);
    sWm[co][ci] = wv.x; sWm[co][ci+1] = wv.y; sWm[co][ci+2] = wv.z; sWm[co][ci+3] = wv.w;
    if (tid < 32) sbm[tid] = bm[tid];
  }

  // QM B-frags: B[k=c][n=i=c32], c = ch*16 + 8*h5 + e
  s8v bqf[2][2];
  {
    const float* qr = q + ((size_t)bt*LL + it + c32)*CC + 8*h5;
    float qp[2][8];
    #pragma unroll
    for (int ch = 0; ch < 2; ++ch) {
      float4 qa = *reinterpret_cast<const float4*>(qr + ch*16);
      float4 qb = *reinterpret_cast<const float4*>(qr + ch*16 + 4);
      qp[ch][0]=qa.x; qp[ch][1]=qa.y; qp[ch][2]=qa.z; qp[ch][3]=qa.w;
      qp[ch][4]=qb.x; qp[ch][5]=qb.y; qp[ch][6]=qb.z; qp[ch][7]=qb.w;
    }
    #pragma unroll
    for (int hh = 0; hh < 2; ++hh) {
      const int H = Hb + hh;
      #pragma unroll
      for (int ch = 0; ch < 2; ++ch) {
        float wlA = Wl[(ch*4 + 2*h5)*HH + H];
        float wlB = Wl[(ch*4 + 2*h5 + 1)*HH + H];
        i4v u;
        u[0] = (int)cvtpk(qp[ch][0]*wlA, qp[ch][1]*wlA);
        u[1] = (int)cvtpk(qp[ch][2]*wlA, qp[ch][3]*wlA);
        u[2] = (int)cvtpk(qp[ch][4]*wlB, qp[ch][5]*wlB);
        u[3] = (int)cvtpk(qp[ch][6]*wlB, qp[ch][7]*wlB);
        bqf[hh][ch] = __builtin_bit_cast(s8v, u);
      }
    }
  }
  __syncthreads();   // smb/sWm visible

  // tiled bases: K frag at kb2[(bt*2+ch)*512 + j][8h5]; V frag at vt2[(bt*32+jc)*32+c32][8h5]
  const short* kch0 = kb + ((size_t)bt*2)*LL*16 + (size_t)c32*16 + 8*h5;
  const short* kch1 = kch0 + (size_t)LL*16;
  const short* vbase = vt + (((size_t)bt*32)*CC + c32)*16 + 8*h5;
  const int sxw = 31 - c32;          // + j gives smb index
  const int xaddr = (lane ^ 32) << 2;  // cross-half bpermute addr

  f16v tacc[2];
  float den[2];
  #pragma unroll
  for (int hh = 0; hh < 2; ++hh) {
    #pragma unroll
    for (int e = 0; e < 16; ++e) tacc[hh][e] = 0.f;
    den[hh] = 0.f;
  }

  #pragma unroll 4
  for (int jp = 0; jp < 16; ++jp) {
    const int j0 = jp*32;
    s8v kf0 = *reinterpret_cast<const s8v*>(kch0 + (size_t)j0*16);
    s8v kf1 = *reinterpret_cast<const s8v*>(kch1 + (size_t)j0*16);
    s8v vf0 = *reinterpret_cast<const s8v*>(vbase + (size_t)(2*jp)*CC*16);
    s8v vf1 = *reinterpret_cast<const s8v*>(vbase + (size_t)(2*jp+1)*CC*16);

    #pragma unroll
    for (int hh = 0; hh < 2; ++hh) {
      const int H = Hb + hh;
      const float* mb = &smb[H][sxw + j0 + 4*h5];
      f16v d;
      #pragma unroll
      for (int G = 0; G < 4; ++G) {
        d[4*G]   = mb[8*G];
        d[4*G+1] = mb[8*G+1];
        d[4*G+2] = mb[8*G+2];
        d[4*G+3] = mb[8*G+3];
      }
      d = __builtin_amdgcn_mfma_f32_32x32x16_bf16(kf0, bqf[hh][0], d, 0, 0, 0);
      d = __builtin_amdgcn_mfma_f32_32x32x16_bf16(kf1, bqf[hh][1], d, 0, 0, 0);

      float ex[16];
      float dsum = 0.f;
      #pragma unroll
      for (int e = 0; e < 16; ++e) { ex[e] = EXP2(d[e]); dsum += ex[e]; }
      den[hh] += dsum;
      unsigned wd[8];
      #pragma unroll
      for (int p = 0; p < 8; ++p) wd[p] = cvtpk(ex[2*p], ex[2*p+1]);

      #pragma unroll
      for (int tt = 0; tt < 2; ++tt) {
        unsigned sa = h5 ? wd[4*tt]     : wd[4*tt+2];
        unsigned sb = h5 ? wd[4*tt+1]   : wd[4*tt+3];
        int ra = __builtin_amdgcn_ds_bpermute(xaddr, (int)sa);
        int rb = __builtin_amdgcn_ds_bpermute(xaddr, (int)sb);
        i4v pw;
        pw[0] = h5 ? ra : (int)wd[4*tt];
        pw[1] = h5 ? rb : (int)wd[4*tt+1];
        pw[2] = h5 ? (int)wd[4*tt+2] : ra;
        pw[3] = h5 ? (int)wd[4*tt+3] : rb;
        s8v pf = __builtin_bit_cast(s8v, pw);
        tacc[hh] = __builtin_amdgcn_mfma_f32_32x32x16_bf16(tt ? vf1 : vf0, pf,
                                                           tacc[hh], 0, 0, 0);
      }
    }
  }

  // epilogue: lane-local inv (i = c32), fold Wc/S; c(reg)=(reg&3)+8(reg>>2)+4h5
  f4v fin[4];
  #pragma unroll
  for (int G = 0; G < 4; ++G) fin[G] = (f4v){0.f,0.f,0.f,0.f};
  #pragma unroll
  for (int hh = 0; hh < 2; ++hh) {
    const int H = Hb + hh;
    float dn = den[hh];
    dn += __shfl_xor(dn, 32);
    float inv = __builtin_amdgcn_rcpf(dn);
    #pragma unroll
    for (int G = 0; G < 4; ++G) {
      float sc = inv * Wc[H*HH + 2*G + h5];   // H' = c>>2 = 2G + h5
      #pragma unroll
      for (int r = 0; r < 4; ++r)
        fin[G][r] += tacc[hh][4*G + r] * sc;
    }
  }

  // combine 4 wave-partials (different head pairs): waves 1..3 write, wave 0 sums
  if (w > 0) {
    #pragma unroll
    for (int G = 0; G < 4; ++G)
      *reinterpret_cast<float4*>(&xch[w-1][lane][4*G]) =
          make_float4(fin[G][0], fin[G][1], fin[G][2], fin[G][3]);
  }
  __syncthreads();
  if (w == 0) {
    #pragma unroll
    for (int G = 0; G < 4; ++G) {
      #pragma unroll
      for (int r = 0; r < 4; ++r) {
        float v = fin[G][r] + xch[0][lane][4*G+r] + xch[1][lane][4*G+r]
                            + xch[2][lane][4*G+r];
        const int c = r + 8*G + 4*h5;
        xt[c32][c] = v;
      }
    }
  }
  __syncthreads();

  // in-block Wm: 1024 outputs over 256 threads (4 co each, one row)
  {
    const int row = tid & 31;
    const int cos = (tid >> 5) * 4;
    float a0 = sbm[cos], a1 = sbm[cos+1], a2 = sbm[cos+2], a3 = sbm[cos+3];
    #pragma unroll
    for (int c = 0; c < CC; ++c) {
      float xv = xt[row][c];
      a0 += xv * sWm[cos][c];
      a1 += xv * sWm[cos+1][c];
      a2 += xv * sWm[cos+2][c];
      a3 += xv * sWm[cos+3][c];
    }
    const int l = it + row;
    float av[4] = {a0, a1, a2, a3};
    #pragma unroll
    for (int u = 0; u < 4; ++u) {
      int co = cos + u;
      if (t < TT-1) out[((b*CC + co)*TT + t)*LL + l] = av[u];
      else          xm8[(b*CC + co)*LL + l] = av[u];
    }
  }
}

// ---------------- fused conv+BN+ReLU+token-linear+subtract (1024 thr, 2-way split) --------
__global__ __launch_bounds__(1024) void convpl_kernel(
    const float* __restrict__ out_in, const float* __restrict__ pp,
    const float* __restrict__ cw, const float* __restrict__ cb,
    const float* __restrict__ bng, const float* __restrict__ bnb,
    const float* __restrict__ plwT, const float* __restrict__ plb,
    const float* __restrict__ xm8, float* __restrict__ out) {
  __shared__ float sy[LL];
  __shared__ float part[2][LL];
  int bc = blockIdx.x;            // b*32 + co
  int b = bc >> 5, co = bc & 31;
  int tid = threadIdx.x;
  int l = tid & (LL-1);
  int h = tid >> 9;               // 0,1

  float acc = (h == 0) ? cb[co] : 0.f;
  #pragma unroll
  for (int cc = 0; cc < 16; ++cc) {
    int ci = h*16 + cc;
    const float* base = out_in + ((b*CC + ci)*TT)*LL + l;
    const float* wv = cw + (co*CC + ci)*TT;
    #pragma unroll
    for (int tq = 0; tq < TT-1; ++tq) acc += base[tq*LL] * wv[tq];
    acc += pp[ci*LL + l] * wv[TT-1];
  }
  part[h][l] = acc;
  __syncthreads();
  if (h == 0) {
    float scale = bng[co] * 0.999995000037499687f;   // 1/sqrt(1+1e-5)
    sy[l] = fmaxf((part[0][l] + part[1][l]) * scale + bnb[co], 0.f);
  }
  __syncthreads();
  float accp = (h == 0) ? plb[l] : 0.f;
  #pragma unroll 4
  for (int lq = 0; lq < 256; ++lq) {
    int ll = h*256 + lq;
    accp += sy[ll] * plwT[ll*LL + l];
  }
  part[h][l] = accp;
  __syncthreads();
  if (h == 0)
    out[((b*CC + co)*TT + (TT-1))*LL + l] = xm8[bc*LL + l] - (part[0][l] + part[1][l]);
}

extern "C" void kernel_launch(void* const* d_in, const int* in_sizes, int n_in,
                              void* d_out, int out_size, void* d_ws, size_t ws_size,
                              hipStream_t stream) {
  const float* x    = (const float*)d_in[0];
  const float* Wq   = (const float*)d_in[1];
  const float* bq   = (const float*)d_in[2];
  const float* Wk   = (const float*)d_in[3];
  const float* bk   = (const float*)d_in[4];
  const float* Wv   = (const float*)d_in[5];
  const float* bv   = (const float*)d_in[6];
  const float* Wm   = (const float*)d_in[7];
  const float* bm   = (const float*)d_in[8];
  const float* Wl   = (const float*)d_in[9];
  const float* Wc   = (const float*)d_in[10];
  const float* rpb  = (const float*)d_in[11];
  const float* pp   = (const float*)d_in[12];
  const float* cw   = (const float*)d_in[13];
  const float* cb   = (const float*)d_in[14];
  const float* bng  = (const float*)d_in[15];
  const float* bnb  = (const float*)d_in[16];
  const float* plw  = (const float*)d_in[17];
  const float* plb  = (const float*)d_in[18];
  float* out = (float*)d_out;

  float* ws = (float*)d_ws;
  const size_t NE = (size_t)NBT*LL*CC;         // 1179648
  float* q_ws   = ws;                          // NE fp32 [bt][l][32]
  short* kb_ws  = (short*)(q_ws + NE);         // NE bf16 kb2[bt][2][512][16]
  short* vt_ws  = kb_ws + NE;                  // NE bf16 vt2[bt][32][32][16]
  float* xm8    = (float*)(vt_ws + NE);        // 131072
  float* plwT   = xm8 + (size_t)BB*CC*LL;      // 262144
  float* mbias  = plwT + (size_t)LL*LL;        // 8*1024

  pre_kernel<<<836, 256, 0, stream>>>(x, Wq, bq, Wk, bk, Wv, bv,
                                      q_ws, kb_ws, vt_ws,
                                      plw, plwT, rpb, Wl, mbias);
  attn_kernel<<<NBT*16, 256, 0, stream>>>(q_ws, kb_ws, vt_ws, Wl, Wc, mbias,
                                          Wm, bm, out, xm8);
  convpl_kernel<<<BB*CC, 1024, 0, stream>>>(out, pp, cw, cb, bng, bnb,
                                            plwT, plb, xm8, out);
}

// Round 22
// 89.572 us; speedup vs baseline: 1.0622x; 1.0622x over previous
//
#include <hip/hip_runtime.h>
#include <math.h>

#define BB 8
#define CC 32
#define TT 9
#define LL 512
#define HH 8
#define DD 4
#define NBT (BB*TT)          // 72
#define RELN (2*LL-1)        // 1023
#define RLN2 1.4426950408889634f
#define SMBW 544             // staged bias window width per head

typedef float  f4v  __attribute__((ext_vector_type(4)));
typedef float  f16v __attribute__((ext_vector_type(16)));
typedef int    i4v  __attribute__((ext_vector_type(4)));
typedef short  s8v  __attribute__((ext_vector_type(8)));   // 8 bf16 = 4 VGPRs

#define EXP2(x) __builtin_amdgcn_exp2f(x)   // raw v_exp_f32

__device__ __forceinline__ unsigned cvtpk(float lo, float hi) {
  unsigned u;
  asm("v_cvt_pk_bf16_f32 %0, %1, %2" : "=v"(u) : "v"(lo), "v"(hi));
  return u;
}

// ---------------- fused pre: proj (blocks 0..575) + pl_w transpose (576..831) + bias (832..835)
// K layout: kb2[bt][ch=c>>4][j=512][c16]  (fragment loads -> contiguous 1KB/wave)
// V layout: vt2[bt][j>>4][c=32][j&15]     (fragment loads -> contiguous 1KB/wave)
__global__ __launch_bounds__(256) void pre_kernel(
    const float* __restrict__ x,
    const float* __restrict__ Wq, const float* __restrict__ bq,
    const float* __restrict__ Wk, const float* __restrict__ bk,
    const float* __restrict__ Wv, const float* __restrict__ bv,
    float* __restrict__ qo, short* __restrict__ kbo, short* __restrict__ vt,
    const float* __restrict__ plw, float* __restrict__ plwT,
    const float* __restrict__ rpb, const float* __restrict__ Wl,
    float* __restrict__ mbr) {
  __shared__ float tile[32][33];
  if (blockIdx.x >= 576) {
    int pid = blockIdx.x - 576;
    if (pid < 256) {
      int bx = (pid & 15) * 32, by = (pid >> 4) * 32;
      int tx = threadIdx.x & 31, ty = threadIdx.x >> 5;   // 32x8
      #pragma unroll
      for (int yy = ty; yy < 32; yy += 8)
        tile[yy][tx] = plw[(by + yy)*LL + bx + tx];
      __syncthreads();
      #pragma unroll
      for (int yy = ty; yy < 32; yy += 8)
        plwT[(bx + yy)*LL + by + tx] = tile[tx][yy];
    } else {
      int xx = (pid - 256) * 256 + threadIdx.x;
      if (xx >= RELN) return;
      int idx = 1022 - xx;
      float r[HH];
      #pragma unroll
      for (int h = 0; h < HH; ++h) r[h] = rpb[h*RELN + idx];
      #pragma unroll
      for (int Ho = 0; Ho < HH; ++Ho) {
        float acc = 0.f;
        #pragma unroll
        for (int h = 0; h < HH; ++h) acc += r[h] * Wl[h*HH + Ho];
        mbr[Ho*1024 + xx] = RLN2 * acc;
      }
    }
    return;
  }

  int bid = blockIdx.x;                 // 0..575
  int gidx = (bid % 144) * 256 + threadIdx.x;    // 0..36863
  int l  = gidx & (LL-1);
  int bt = gidx >> 9;
  int b = bt / TT, t = bt - b*TT;
  const int hq = (bid / 144) * 2;       // first head of this quarter

  float xv[CC];
  #pragma unroll
  for (int c = 0; c < CC; ++c)
    xv[c] = x[((b*CC + c)*TT + t)*LL + l];

  // Q (scaled by 0.5*log2e)
  #pragma unroll
  for (int h = hq; h < hq + 2; ++h) {
    float yv[DD];
    #pragma unroll
    for (int d = 0; d < DD; ++d) {
      int co = h*DD + d;
      float acc = bq[co];
      #pragma unroll
      for (int ci = 0; ci < CC; ++ci) acc += xv[ci] * Wq[co*CC + ci];
      yv[d] = acc;
    }
    float n = sqrtf(yv[0]*yv[0] + yv[1]*yv[1] + yv[2]*yv[2] + yv[3]*yv[3]);
    float inv = 0.5f * RLN2 / fmaxf(n, 1e-12f);
    *reinterpret_cast<float4*>(&qo[((size_t)bt*LL + l)*CC + h*DD]) =
        make_float4(yv[0]*inv, yv[1]*inv, yv[2]*inv, yv[3]*inv);
  }
  // K -> bf16 tiled: kb2[bt][hq>>2][l][(hq&3)*4 .. +8)
  {
    unsigned ku[4];
    #pragma unroll
    for (int hh = 0; hh < 2; ++hh) {
      int h = hq + hh;
      float yv[DD];
      #pragma unroll
      for (int d = 0; d < DD; ++d) {
        int co = h*DD + d;
        float acc = bk[co];
        #pragma unroll
        for (int ci = 0; ci < CC; ++ci) acc += xv[ci] * Wk[co*CC + ci];
        yv[d] = acc;
      }
      float n = sqrtf(yv[0]*yv[0] + yv[1]*yv[1] + yv[2]*yv[2] + yv[3]*yv[3]);
      float inv = 1.0f / fmaxf(n, 1e-12f);
      ku[hh*2]   = cvtpk(yv[0]*inv, yv[1]*inv);
      ku[hh*2+1] = cvtpk(yv[2]*inv, yv[3]*inv);
    }
    const int ch = hq >> 2;
    const int c16b = (hq & 3) * 4;
    *reinterpret_cast<uint4*>(kbo + (((size_t)bt*2 + ch)*LL + l)*16 + c16b) =
        make_uint4(ku[0], ku[1], ku[2], ku[3]);
  }
  // V -> bf16 chunk-tiled: vt2[bt][l>>4][c][l&15]
  #pragma unroll
  for (int h = hq; h < hq + 2; ++h) {
    float yv[DD];
    #pragma unroll
    for (int d = 0; d < DD; ++d) {
      int co = h*DD + d;
      float acc = bv[co];
      #pragma unroll
      for (int ci = 0; ci < CC; ++ci) acc += xv[ci] * Wv[co*CC + ci];
      yv[d] = acc;
    }
    float n = sqrtf(yv[0]*yv[0] + yv[1]*yv[1] + yv[2]*yv[2] + yv[3]*yv[3]);
    float inv = 1.0f / fmaxf(n, 1e-12f);
    #pragma unroll
    for (int d = 0; d < DD; ++d) {
      unsigned u = cvtpk(yv[d]*inv, yv[d]*inv);
      int co = h*DD + d;
      reinterpret_cast<unsigned short*>(vt)[
          (((size_t)bt*32 + (l >> 4))*CC + co)*16 + (l & 15)] =
          (unsigned short)(u & 0xffffu);
    }
  }
}

// ---------------- fused attention + Wm (v20 final: 32x32x16 MFMA, unroll 2) ----------
// 1152 blocks x 256 thr. Block = (bt, 32-row i-block). Wave w: ALL 32 i, heads {2w,2w+1}.
// Lane: c32=lane&31, h5=lane>>5. QK: D[j][i]=K·QM+bias, j=(reg&3)+8(reg>>2)+4h5 [m74],
// i=c32. PV: O^T[c][i] = V^T · P^T via cross-half word exchange (2 bpermute per t).
// K/V fragment loads are contiguous 1KB wave transactions (tiled layouts from pre).
// NOTE: unroll 2 is the scheduling optimum (unroll 4 -> VGPR clamp 88, -11%; unroll 1
// -> 2 chains only, -6%). Do not change without re-measuring.
__global__ __launch_bounds__(256, 2) void attn_kernel(
    const float* __restrict__ q, const short* __restrict__ kb,
    const short* __restrict__ vt,
    const float* __restrict__ Wl, const float* __restrict__ Wc,
    const float* __restrict__ mbr,
    const float* __restrict__ Wm, const float* __restrict__ bm,
    float* __restrict__ out, float* __restrict__ xm8) {
  __shared__ float smb[HH][SMBW];   // 17.4 KB staged bias
  __shared__ float xch[3][64][17];  // non-leader partials, padded
  __shared__ float xt[32][33];      // x_att tile [i][c], padded
  __shared__ float sWm[32][33];     // Wm[co][ci], padded
  __shared__ float sbm[32];

  const int wgid = blockIdx.x;
  const int id   = (wgid & 7) * 144 + (wgid >> 3);   // 1152 % 8 == 0 -> bijective
  const int bt   = id >> 4;       // [0,72)
  const int iblk = id & 15;       // 32-row block
  const int b    = bt / TT, t = bt - b*TT;

  const int tid  = threadIdx.x;
  const int w    = __builtin_amdgcn_readfirstlane(tid >> 6);
  const int lane = tid & 63;
  const int c32  = lane & 31;
  const int h5   = lane >> 5;     // 0,1
  const int it   = iblk*32;
  const int Hb   = 2*w;           // wave's 2 heads

  // stage bias window
  {
    const int xbase = 480 - 32*iblk;
    for (int s = tid; s < HH*SMBW; s += 256) {
      int h = s / SMBW, sx = s - h*SMBW;
      smb[h][sx] = mbr[h*1024 + xbase + sx];
    }
  }
  // preload Wm/bm -> LDS
  {
    int c4 = tid * 4;
    int co = c4 >> 5, ci = c4 & 31;
    float4 wv = *reinterpret_cast<const float4*>(Wm + co*CC + ci);
    sWm[co][ci] = wv.x; sWm[co][ci+1] = wv.y; sWm[co][ci+2] = wv.z; sWm[co][ci+3] = wv.w;
    if (tid < 32) sbm[tid] = bm[tid];
  }

  // QM B-frags: B[k=c][n=i=c32], c = ch*16 + 8*h5 + e
  s8v bqf[2][2];
  {
    const float* qr = q + ((size_t)bt*LL + it + c32)*CC + 8*h5;
    float qp[2][8];
    #pragma unroll
    for (int ch = 0; ch < 2; ++ch) {
      float4 qa = *reinterpret_cast<const float4*>(qr + ch*16);
      float4 qb = *reinterpret_cast<const float4*>(qr + ch*16 + 4);
      qp[ch][0]=qa.x; qp[ch][1]=qa.y; qp[ch][2]=qa.z; qp[ch][3]=qa.w;
      qp[ch][4]=qb.x; qp[ch][5]=qb.y; qp[ch][6]=qb.z; qp[ch][7]=qb.w;
    }
    #pragma unroll
    for (int hh = 0; hh < 2; ++hh) {
      const int H = Hb + hh;
      #pragma unroll
      for (int ch = 0; ch < 2; ++ch) {
        float wlA = Wl[(ch*4 + 2*h5)*HH + H];
        float wlB = Wl[(ch*4 + 2*h5 + 1)*HH + H];
        i4v u;
        u[0] = (int)cvtpk(qp[ch][0]*wlA, qp[ch][1]*wlA);
        u[1] = (int)cvtpk(qp[ch][2]*wlA, qp[ch][3]*wlA);
        u[2] = (int)cvtpk(qp[ch][4]*wlB, qp[ch][5]*wlB);
        u[3] = (int)cvtpk(qp[ch][6]*wlB, qp[ch][7]*wlB);
        bqf[hh][ch] = __builtin_bit_cast(s8v, u);
      }
    }
  }
  __syncthreads();   // smb/sWm visible

  // tiled bases: K frag at kb2[(bt*2+ch)*512 + j][8h5]; V frag at vt2[(bt*32+jc)*32+c32][8h5]
  const short* kch0 = kb + ((size_t)bt*2)*LL*16 + (size_t)c32*16 + 8*h5;
  const short* kch1 = kch0 + (size_t)LL*16;
  const short* vbase = vt + (((size_t)bt*32)*CC + c32)*16 + 8*h5;
  const int sxw = 31 - c32;          // + j gives smb index
  const int xaddr = (lane ^ 32) << 2;  // cross-half bpermute addr

  f16v tacc[2];
  float den[2];
  #pragma unroll
  for (int hh = 0; hh < 2; ++hh) {
    #pragma unroll
    for (int e = 0; e < 16; ++e) tacc[hh][e] = 0.f;
    den[hh] = 0.f;
  }

  #pragma unroll 2
  for (int jp = 0; jp < 16; ++jp) {
    const int j0 = jp*32;
    s8v kf0 = *reinterpret_cast<const s8v*>(kch0 + (size_t)j0*16);
    s8v kf1 = *reinterpret_cast<const s8v*>(kch1 + (size_t)j0*16);
    s8v vf0 = *reinterpret_cast<const s8v*>(vbase + (size_t)(2*jp)*CC*16);
    s8v vf1 = *reinterpret_cast<const s8v*>(vbase + (size_t)(2*jp+1)*CC*16);

    #pragma unroll
    for (int hh = 0; hh < 2; ++hh) {
      const int H = Hb + hh;
      const float* mb = &smb[H][sxw + j0 + 4*h5];
      f16v d;
      #pragma unroll
      for (int G = 0; G < 4; ++G) {
        d[4*G]   = mb[8*G];
        d[4*G+1] = mb[8*G+1];
        d[4*G+2] = mb[8*G+2];
        d[4*G+3] = mb[8*G+3];
      }
      d = __builtin_amdgcn_mfma_f32_32x32x16_bf16(kf0, bqf[hh][0], d, 0, 0, 0);
      d = __builtin_amdgcn_mfma_f32_32x32x16_bf16(kf1, bqf[hh][1], d, 0, 0, 0);

      float ex[16];
      float dsum = 0.f;
      #pragma unroll
      for (int e = 0; e < 16; ++e) { ex[e] = EXP2(d[e]); dsum += ex[e]; }
      den[hh] += dsum;
      unsigned wd[8];
      #pragma unroll
      for (int p = 0; p < 8; ++p) wd[p] = cvtpk(ex[2*p], ex[2*p+1]);

      #pragma unroll
      for (int tt = 0; tt < 2; ++tt) {
        unsigned sa = h5 ? wd[4*tt]     : wd[4*tt+2];
        unsigned sb = h5 ? wd[4*tt+1]   : wd[4*tt+3];
        int ra = __builtin_amdgcn_ds_bpermute(xaddr, (int)sa);
        int rb = __builtin_amdgcn_ds_bpermute(xaddr, (int)sb);
        i4v pw;
        pw[0] = h5 ? ra : (int)wd[4*tt];
        pw[1] = h5 ? rb : (int)wd[4*tt+1];
        pw[2] = h5 ? (int)wd[4*tt+2] : ra;
        pw[3] = h5 ? (int)wd[4*tt+3] : rb;
        s8v pf = __builtin_bit_cast(s8v, pw);
        tacc[hh] = __builtin_amdgcn_mfma_f32_32x32x16_bf16(tt ? vf1 : vf0, pf,
                                                           tacc[hh], 0, 0, 0);
      }
    }
  }

  // epilogue: lane-local inv (i = c32), fold Wc/S; c(reg)=(reg&3)+8(reg>>2)+4h5
  f4v fin[4];
  #pragma unroll
  for (int G = 0; G < 4; ++G) fin[G] = (f4v){0.f,0.f,0.f,0.f};
  #pragma unroll
  for (int hh = 0; hh < 2; ++hh) {
    const int H = Hb + hh;
    float dn = den[hh];
    dn += __shfl_xor(dn, 32);
    float inv = __builtin_amdgcn_rcpf(dn);
    #pragma unroll
    for (int G = 0; G < 4; ++G) {
      float sc = inv * Wc[H*HH + 2*G + h5];   // H' = c>>2 = 2G + h5
      #pragma unroll
      for (int r = 0; r < 4; ++r)
        fin[G][r] += tacc[hh][4*G + r] * sc;
    }
  }

  // combine 4 wave-partials (different head pairs): waves 1..3 write, wave 0 sums
  if (w > 0) {
    #pragma unroll
    for (int G = 0; G < 4; ++G)
      *reinterpret_cast<float4*>(&xch[w-1][lane][4*G]) =
          make_float4(fin[G][0], fin[G][1], fin[G][2], fin[G][3]);
  }
  __syncthreads();
  if (w == 0) {
    #pragma unroll
    for (int G = 0; G < 4; ++G) {
      #pragma unroll
      for (int r = 0; r < 4; ++r) {
        float v = fin[G][r] + xch[0][lane][4*G+r] + xch[1][lane][4*G+r]
                            + xch[2][lane][4*G+r];
        const int c = r + 8*G + 4*h5;
        xt[c32][c] = v;
      }
    }
  }
  __syncthreads();

  // in-block Wm: 1024 outputs over 256 threads (4 co each, one row)
  {
    const int row = tid & 31;
    const int cos = (tid >> 5) * 4;
    float a0 = sbm[cos], a1 = sbm[cos+1], a2 = sbm[cos+2], a3 = sbm[cos+3];
    #pragma unroll
    for (int c = 0; c < CC; ++c) {
      float xv = xt[row][c];
      a0 += xv * sWm[cos][c];
      a1 += xv * sWm[cos+1][c];
      a2 += xv * sWm[cos+2][c];
      a3 += xv * sWm[cos+3][c];
    }
    const int l = it + row;
    float av[4] = {a0, a1, a2, a3};
    #pragma unroll
    for (int u = 0; u < 4; ++u) {
      int co = cos + u;
      if (t < TT-1) out[((b*CC + co)*TT + t)*LL + l] = av[u];
      else          xm8[(b*CC + co)*LL + l] = av[u];
    }
  }
}

// ---------------- fused conv+BN+ReLU+token-linear+subtract (1024 thr, 2-way split) --------
__global__ __launch_bounds__(1024) void convpl_kernel(
    const float* __restrict__ out_in, const float* __restrict__ pp,
    const float* __restrict__ cw, const float* __restrict__ cb,
    const float* __restrict__ bng, const float* __restrict__ bnb,
    const float* __restrict__ plwT, const float* __restrict__ plb,
    const float* __restrict__ xm8, float* __restrict__ out) {
  __shared__ float sy[LL];
  __shared__ float part[2][LL];
  int bc = blockIdx.x;            // b*32 + co
  int b = bc >> 5, co = bc & 31;
  int tid = threadIdx.x;
  int l = tid & (LL-1);
  int h = tid >> 9;               // 0,1

  float acc = (h == 0) ? cb[co] : 0.f;
  #pragma unroll
  for (int cc = 0; cc < 16; ++cc) {
    int ci = h*16 + cc;
    const float* base = out_in + ((b*CC + ci)*TT)*LL + l;
    const float* wv = cw + (co*CC + ci)*TT;
    #pragma unroll
    for (int tq = 0; tq < TT-1; ++tq) acc += base[tq*LL] * wv[tq];
    acc += pp[ci*LL + l] * wv[TT-1];
  }
  part[h][l] = acc;
  __syncthreads();
  if (h == 0) {
    float scale = bng[co] * 0.999995000037499687f;   // 1/sqrt(1+1e-5)
    sy[l] = fmaxf((part[0][l] + part[1][l]) * scale + bnb[co], 0.f);
  }
  __syncthreads();
  float accp = (h == 0) ? plb[l] : 0.f;
  #pragma unroll 4
  for (int lq = 0; lq < 256; ++lq) {
    int ll = h*256 + lq;
    accp += sy[ll] * plwT[ll*LL + l];
  }
  part[h][l] = accp;
  __syncthreads();
  if (h == 0)
    out[((b*CC + co)*TT + (TT-1))*LL + l] = xm8[bc*LL + l] - (part[0][l] + part[1][l]);
}

extern "C" void kernel_launch(void* const* d_in, const int* in_sizes, int n_in,
                              void* d_out, int out_size, void* d_ws, size_t ws_size,
                              hipStream_t stream) {
  const float* x    = (const float*)d_in[0];
  const float* Wq   = (const float*)d_in[1];
  const float* bq   = (const float*)d_in[2];
  const float* Wk   = (const float*)d_in[3];
  const float* bk   = (const float*)d_in[4];
  const float* Wv   = (const float*)d_in[5];
  const float* bv   = (const float*)d_in[6];
  const float* Wm   = (const float*)d_in[7];
  const float* bm   = (const float*)d_in[8];
  const float* Wl   = (const float*)d_in[9];
  const float* Wc   = (const float*)d_in[10];
  const float* rpb  = (const float*)d_in[11];
  const float* pp   = (const float*)d_in[12];
  const float* cw   = (const float*)d_in[13];
  const float* cb   = (const float*)d_in[14];
  const float* bng  = (const float*)d_in[15];
  const float* bnb  = (const float*)d_in[16];
  const float* plw  = (const float*)d_in[17];
  const float* plb  = (const float*)d_in[18];
  float* out = (float*)d_out;

  float* ws = (float*)d_ws;
  const size_t NE = (size_t)NBT*LL*CC;         // 1179648
  float* q_ws   = ws;                          // NE fp32 [bt][l][32]
  short* kb_ws  = (short*)(q_ws + NE);         // NE bf16 kb2[bt][2][512][16]
  short* vt_ws  = kb_ws + NE;                  // NE bf16 vt2[bt][32][32][16]
  float* xm8    = (float*)(vt_ws + NE);        // 131072
  float* plwT   = xm8 + (size_t)BB*CC*LL;      // 262144
  float* mbias  = plwT + (size_t)LL*LL;        // 8*1024

  pre_kernel<<<836, 256, 0, stream>>>(x, Wq, bq, Wk, bk, Wv, bv,
                                      q_ws, kb_ws, vt_ws,
                                      plw, plwT, rpb, Wl, mbias);
  attn_kernel<<<NBT*16, 256, 0, stream>>>(q_ws, kb_ws, vt_ws, Wl, Wc, mbias,
                                          Wm, bm, out, xm8);
  convpl_kernel<<<BB*CC, 1024, 0, stream>>>(out, pp, cw, cb, bng, bnb,
                                            plwT, plb, xm8, out);
}

// Round 25
// 89.489 us; speedup vs baseline: 1.0632x; 1.0009x over previous
//
#include <hip/hip_runtime.h>
#include <math.h>

#define BB 8
#define CC 32
#define TT 9
#define LL 512
#define HH 8
#define DD 4
#define NBT (BB*TT)          // 72
#define RELN (2*LL-1)        // 1023
#define RLN2 1.4426950408889634f
#define SMBW 544             // staged bias window width per head

typedef float  f4v  __attribute__((ext_vector_type(4)));
typedef float  f16v __attribute__((ext_vector_type(16)));
typedef int    i4v  __attribute__((ext_vector_type(4)));
typedef short  s8v  __attribute__((ext_vector_type(8)));   // 8 bf16 = 4 VGPRs

#define EXP2(x) __builtin_amdgcn_exp2f(x)   // raw v_exp_f32

__device__ __forceinline__ unsigned cvtpk(float lo, float hi) {
  unsigned u;
  asm("v_cvt_pk_bf16_f32 %0, %1, %2" : "=v"(u) : "v"(lo), "v"(hi));
  return u;
}

// ---------------- fused pre: proj (blocks 0..575) + pl_w transpose (576..831) + bias (832..835)
// K layout: kb2[bt][ch=c>>4][j=512][c16]  (fragment loads -> contiguous 1KB/wave)
// V layout: vt2[bt][j>>4][c=32][j&15]     (fragment loads -> contiguous 1KB/wave)
__global__ __launch_bounds__(256) void pre_kernel(
    const float* __restrict__ x,
    const float* __restrict__ Wq, const float* __restrict__ bq,
    const float* __restrict__ Wk, const float* __restrict__ bk,
    const float* __restrict__ Wv, const float* __restrict__ bv,
    float* __restrict__ qo, short* __restrict__ kbo, short* __restrict__ vt,
    const float* __restrict__ plw, float* __restrict__ plwT,
    const float* __restrict__ rpb, const float* __restrict__ Wl,
    float* __restrict__ mbr) {
  __shared__ float tile[32][33];
  if (blockIdx.x >= 576) {
    int pid = blockIdx.x - 576;
    if (pid < 256) {
      int bx = (pid & 15) * 32, by = (pid >> 4) * 32;
      int tx = threadIdx.x & 31, ty = threadIdx.x >> 5;   // 32x8
      #pragma unroll
      for (int yy = ty; yy < 32; yy += 8)
        tile[yy][tx] = plw[(by + yy)*LL + bx + tx];
      __syncthreads();
      #pragma unroll
      for (int yy = ty; yy < 32; yy += 8)
        plwT[(bx + yy)*LL + by + tx] = tile[tx][yy];
    } else {
      int xx = (pid - 256) * 256 + threadIdx.x;
      if (xx >= RELN) return;
      int idx = 1022 - xx;
      float r[HH];
      #pragma unroll
      for (int h = 0; h < HH; ++h) r[h] = rpb[h*RELN + idx];
      #pragma unroll
      for (int Ho = 0; Ho < HH; ++Ho) {
        float acc = 0.f;
        #pragma unroll
        for (int h = 0; h < HH; ++h) acc += r[h] * Wl[h*HH + Ho];
        mbr[Ho*1024 + xx] = RLN2 * acc;
      }
    }
    return;
  }

  int bid = blockIdx.x;                 // 0..575
  int gidx = (bid % 144) * 256 + threadIdx.x;    // 0..36863
  int l  = gidx & (LL-1);
  int bt = gidx >> 9;
  int b = bt / TT, t = bt - b*TT;
  const int hq = (bid / 144) * 2;       // first head of this quarter

  float xv[CC];
  #pragma unroll
  for (int c = 0; c < CC; ++c)
    xv[c] = x[((b*CC + c)*TT + t)*LL + l];

  // Q (scaled by 0.5*log2e)
  #pragma unroll
  for (int h = hq; h < hq + 2; ++h) {
    float yv[DD];
    #pragma unroll
    for (int d = 0; d < DD; ++d) {
      int co = h*DD + d;
      float acc = bq[co];
      #pragma unroll
      for (int ci = 0; ci < CC; ++ci) acc += xv[ci] * Wq[co*CC + ci];
      yv[d] = acc;
    }
    float n = sqrtf(yv[0]*yv[0] + yv[1]*yv[1] + yv[2]*yv[2] + yv[3]*yv[3]);
    float inv = 0.5f * RLN2 / fmaxf(n, 1e-12f);
    *reinterpret_cast<float4*>(&qo[((size_t)bt*LL + l)*CC + h*DD]) =
        make_float4(yv[0]*inv, yv[1]*inv, yv[2]*inv, yv[3]*inv);
  }
  // K -> bf16 tiled: kb2[bt][hq>>2][l][(hq&3)*4 .. +8)
  {
    unsigned ku[4];
    #pragma unroll
    for (int hh = 0; hh < 2; ++hh) {
      int h = hq + hh;
      float yv[DD];
      #pragma unroll
      for (int d = 0; d < DD; ++d) {
        int co = h*DD + d;
        float acc = bk[co];
        #pragma unroll
        for (int ci = 0; ci < CC; ++ci) acc += xv[ci] * Wk[co*CC + ci];
        yv[d] = acc;
      }
      float n = sqrtf(yv[0]*yv[0] + yv[1]*yv[1] + yv[2]*yv[2] + yv[3]*yv[3]);
      float inv = 1.0f / fmaxf(n, 1e-12f);
      ku[hh*2]   = cvtpk(yv[0]*inv, yv[1]*inv);
      ku[hh*2+1] = cvtpk(yv[2]*inv, yv[3]*inv);
    }
    const int ch = hq >> 2;
    const int c16b = (hq & 3) * 4;
    *reinterpret_cast<uint4*>(kbo + (((size_t)bt*2 + ch)*LL + l)*16 + c16b) =
        make_uint4(ku[0], ku[1], ku[2], ku[3]);
  }
  // V -> bf16 chunk-tiled: vt2[bt][l>>4][c][l&15]
  #pragma unroll
  for (int h = hq; h < hq + 2; ++h) {
    float yv[DD];
    #pragma unroll
    for (int d = 0; d < DD; ++d) {
      int co = h*DD + d;
      float acc = bv[co];
      #pragma unroll
      for (int ci = 0; ci < CC; ++ci) acc += xv[ci] * Wv[co*CC + ci];
      yv[d] = acc;
    }
    float n = sqrtf(yv[0]*yv[0] + yv[1]*yv[1] + yv[2]*yv[2] + yv[3]*yv[3]);
    float inv = 1.0f / fmaxf(n, 1e-12f);
    #pragma unroll
    for (int d = 0; d < DD; ++d) {
      unsigned u = cvtpk(yv[d]*inv, yv[d]*inv);
      int co = h*DD + d;
      reinterpret_cast<unsigned short*>(vt)[
          (((size_t)bt*32 + (l >> 4))*CC + co)*16 + (l & 15)] =
          (unsigned short)(u & 0xffffu);
    }
  }
}

// ---------------- fused attention + Wm (v20 final: 32x32x16 MFMA, unroll 2) ----------
// 1152 blocks x 256 thr. Block = (bt, 32-row i-block). Wave w: ALL 32 i, heads {2w,2w+1}.
// Lane: c32=lane&31, h5=lane>>5. QK: D[j][i]=K·QM+bias, j=(reg&3)+8(reg>>2)+4h5 [m74],
// i=c32. PV: O^T[c][i] = V^T · P^T via cross-half word exchange (2 bpermute per t).
// K/V fragment loads are contiguous 1KB wave transactions (tiled layouts from pre).
// NOTE: unroll 2 is the scheduling optimum (unroll 4 -> VGPR clamp 88, -11%).
// NOTE: permlane32_swap for the P-exchange failed correctness twice (r23/r24) --
// ds_bpermute version below is verified. Do not re-attempt without HW single-step.
__global__ __launch_bounds__(256, 2) void attn_kernel(
    const float* __restrict__ q, const short* __restrict__ kb,
    const short* __restrict__ vt,
    const float* __restrict__ Wl, const float* __restrict__ Wc,
    const float* __restrict__ mbr,
    const float* __restrict__ Wm, const float* __restrict__ bm,
    float* __restrict__ out, float* __restrict__ xm8) {
  __shared__ float smb[HH][SMBW];   // 17.4 KB staged bias
  __shared__ float xch[3][64][17];  // non-leader partials, padded
  __shared__ float xt[32][33];      // x_att tile [i][c], padded
  __shared__ float sWm[32][33];     // Wm[co][ci], padded
  __shared__ float sbm[32];

  const int wgid = blockIdx.x;
  const int id   = (wgid & 7) * 144 + (wgid >> 3);   // 1152 % 8 == 0 -> bijective
  const int bt   = id >> 4;       // [0,72)
  const int iblk = id & 15;       // 32-row block
  const int b    = bt / TT, t = bt - b*TT;

  const int tid  = threadIdx.x;
  const int w    = __builtin_amdgcn_readfirstlane(tid >> 6);
  const int lane = tid & 63;
  const int c32  = lane & 31;
  const int h5   = lane >> 5;     // 0,1
  const int it   = iblk*32;
  const int Hb   = 2*w;           // wave's 2 heads

  // stage bias window
  {
    const int xbase = 480 - 32*iblk;
    for (int s = tid; s < HH*SMBW; s += 256) {
      int h = s / SMBW, sx = s - h*SMBW;
      smb[h][sx] = mbr[h*1024 + xbase + sx];
    }
  }
  // preload Wm/bm -> LDS
  {
    int c4 = tid * 4;
    int co = c4 >> 5, ci = c4 & 31;
    float4 wv = *reinterpret_cast<const float4*>(Wm + co*CC + ci);
    sWm[co][ci] = wv.x; sWm[co][ci+1] = wv.y; sWm[co][ci+2] = wv.z; sWm[co][ci+3] = wv.w;
    if (tid < 32) sbm[tid] = bm[tid];
  }

  // QM B-frags: B[k=c][n=i=c32], c = ch*16 + 8*h5 + e
  s8v bqf[2][2];
  {
    const float* qr = q + ((size_t)bt*LL + it + c32)*CC + 8*h5;
    float qp[2][8];
    #pragma unroll
    for (int ch = 0; ch < 2; ++ch) {
      float4 qa = *reinterpret_cast<const float4*>(qr + ch*16);
      float4 qb = *reinterpret_cast<const float4*>(qr + ch*16 + 4);
      qp[ch][0]=qa.x; qp[ch][1]=qa.y; qp[ch][2]=qa.z; qp[ch][3]=qa.w;
      qp[ch][4]=qb.x; qp[ch][5]=qb.y; qp[ch][6]=qb.z; qp[ch][7]=qb.w;
    }
    #pragma unroll
    for (int hh = 0; hh < 2; ++hh) {
      const int H = Hb + hh;
      #pragma unroll
      for (int ch = 0; ch < 2; ++ch) {
        float wlA = Wl[(ch*4 + 2*h5)*HH + H];
        float wlB = Wl[(ch*4 + 2*h5 + 1)*HH + H];
        i4v u;
        u[0] = (int)cvtpk(qp[ch][0]*wlA, qp[ch][1]*wlA);
        u[1] = (int)cvtpk(qp[ch][2]*wlA, qp[ch][3]*wlA);
        u[2] = (int)cvtpk(qp[ch][4]*wlB, qp[ch][5]*wlB);
        u[3] = (int)cvtpk(qp[ch][6]*wlB, qp[ch][7]*wlB);
        bqf[hh][ch] = __builtin_bit_cast(s8v, u);
      }
    }
  }
  __syncthreads();   // smb/sWm visible

  // tiled bases: K frag at kb2[(bt*2+ch)*512 + j][8h5]; V frag at vt2[(bt*32+jc)*32+c32][8h5]
  const short* kch0 = kb + ((size_t)bt*2)*LL*16 + (size_t)c32*16 + 8*h5;
  const short* kch1 = kch0 + (size_t)LL*16;
  const short* vbase = vt + (((size_t)bt*32)*CC + c32)*16 + 8*h5;
  const int sxw = 31 - c32;          // + j gives smb index
  const int xaddr = (lane ^ 32) << 2;  // cross-half bpermute addr

  f16v tacc[2];
  float den[2];
  #pragma unroll
  for (int hh = 0; hh < 2; ++hh) {
    #pragma unroll
    for (int e = 0; e < 16; ++e) tacc[hh][e] = 0.f;
    den[hh] = 0.f;
  }

  #pragma unroll 2
  for (int jp = 0; jp < 16; ++jp) {
    const int j0 = jp*32;
    s8v kf0 = *reinterpret_cast<const s8v*>(kch0 + (size_t)j0*16);
    s8v kf1 = *reinterpret_cast<const s8v*>(kch1 + (size_t)j0*16);
    s8v vf0 = *reinterpret_cast<const s8v*>(vbase + (size_t)(2*jp)*CC*16);
    s8v vf1 = *reinterpret_cast<const s8v*>(vbase + (size_t)(2*jp+1)*CC*16);

    #pragma unroll
    for (int hh = 0; hh < 2; ++hh) {
      const int H = Hb + hh;
      const float* mb = &smb[H][sxw + j0 + 4*h5];
      f16v d;
      #pragma unroll
      for (int G = 0; G < 4; ++G) {
        d[4*G]   = mb[8*G];
        d[4*G+1] = mb[8*G+1];
        d[4*G+2] = mb[8*G+2];
        d[4*G+3] = mb[8*G+3];
      }
      d = __builtin_amdgcn_mfma_f32_32x32x16_bf16(kf0, bqf[hh][0], d, 0, 0, 0);
      d = __builtin_amdgcn_mfma_f32_32x32x16_bf16(kf1, bqf[hh][1], d, 0, 0, 0);

      float ex[16];
      float dsum = 0.f;
      #pragma unroll
      for (int e = 0; e < 16; ++e) { ex[e] = EXP2(d[e]); dsum += ex[e]; }
      den[hh] += dsum;
      unsigned wd[8];
      #pragma unroll
      for (int p = 0; p < 8; ++p) wd[p] = cvtpk(ex[2*p], ex[2*p+1]);

      #pragma unroll
      for (int tt = 0; tt < 2; ++tt) {
        unsigned sa = h5 ? wd[4*tt]     : wd[4*tt+2];
        unsigned sb = h5 ? wd[4*tt+1]   : wd[4*tt+3];
        int ra = __builtin_amdgcn_ds_bpermute(xaddr, (int)sa);
        int rb = __builtin_amdgcn_ds_bpermute(xaddr, (int)sb);
        i4v pw;
        pw[0] = h5 ? ra : (int)wd[4*tt];
        pw[1] = h5 ? rb : (int)wd[4*tt+1];
        pw[2] = h5 ? (int)wd[4*tt+2] : ra;
        pw[3] = h5 ? (int)wd[4*tt+3] : rb;
        s8v pf = __builtin_bit_cast(s8v, pw);
        tacc[hh] = __builtin_amdgcn_mfma_f32_32x32x16_bf16(tt ? vf1 : vf0, pf,
                                                           tacc[hh], 0, 0, 0);
      }
    }
  }

  // epilogue: lane-local inv (i = c32), fold Wc/S; c(reg)=(reg&3)+8(reg>>2)+4h5
  f4v fin[4];
  #pragma unroll
  for (int G = 0; G < 4; ++G) fin[G] = (f4v){0.f,0.f,0.f,0.f};
  #pragma unroll
  for (int hh = 0; hh < 2; ++hh) {
    const int H = Hb + hh;
    float dn = den[hh];
    dn += __shfl_xor(dn, 32);
    float inv = __builtin_amdgcn_rcpf(dn);
    #pragma unroll
    for (int G = 0; G < 4; ++G) {
      float sc = inv * Wc[H*HH + 2*G + h5];   // H' = c>>2 = 2G + h5
      #pragma unroll
      for (int r = 0; r < 4; ++r)
        fin[G][r] += tacc[hh][4*G + r] * sc;
    }
  }

  // combine 4 wave-partials (different head pairs): waves 1..3 write, wave 0 sums
  if (w > 0) {
    #pragma unroll
    for (int G = 0; G < 4; ++G)
      *reinterpret_cast<float4*>(&xch[w-1][lane][4*G]) =
          make_float4(fin[G][0], fin[G][1], fin[G][2], fin[G][3]);
  }
  __syncthreads();
  if (w == 0) {
    #pragma unroll
    for (int G = 0; G < 4; ++G) {
      #pragma unroll
      for (int r = 0; r < 4; ++r) {
        float v = fin[G][r] + xch[0][lane][4*G+r] + xch[1][lane][4*G+r]
                            + xch[2][lane][4*G+r];
        const int c = r + 8*G + 4*h5;
        xt[c32][c] = v;
      }
    }
  }
  __syncthreads();

  // in-block Wm: 1024 outputs over 256 threads (4 co each, one row)
  {
    const int row = tid & 31;
    const int cos = (tid >> 5) * 4;
    float a0 = sbm[cos], a1 = sbm[cos+1], a2 = sbm[cos+2], a3 = sbm[cos+3];
    #pragma unroll
    for (int c = 0; c < CC; ++c) {
      float xv = xt[row][c];
      a0 += xv * sWm[cos][c];
      a1 += xv * sWm[cos+1][c];
      a2 += xv * sWm[cos+2][c];
      a3 += xv * sWm[cos+3][c];
    }
    const int l = it + row;
    float av[4] = {a0, a1, a2, a3};
    #pragma unroll
    for (int u = 0; u < 4; ++u) {
      int co = cos + u;
      if (t < TT-1) out[((b*CC + co)*TT + t)*LL + l] = av[u];
      else          xm8[(b*CC + co)*LL + l] = av[u];
    }
  }
}

// ---------------- fused conv+BN+ReLU+token-linear+subtract (1024 thr, 2-way split) --------
__global__ __launch_bounds__(1024) void convpl_kernel(
    const float* __restrict__ out_in, const float* __restrict__ pp,
    const float* __restrict__ cw, const float* __restrict__ cb,
    const float* __restrict__ bng, const float* __restrict__ bnb,
    const float* __restrict__ plwT, const float* __restrict__ plb,
    const float* __restrict__ xm8, float* __restrict__ out) {
  __shared__ float sy[LL];
  __shared__ float part[2][LL];
  int bc = blockIdx.x;            // b*32 + co
  int b = bc >> 5, co = bc & 31;
  int tid = threadIdx.x;
  int l = tid & (LL-1);
  int h = tid >> 9;               // 0,1

  float acc = (h == 0) ? cb[co] : 0.f;
  #pragma unroll
  for (int cc = 0; cc < 16; ++cc) {
    int ci = h*16 + cc;
    const float* base = out_in + ((b*CC + ci)*TT)*LL + l;
    const float* wv = cw + (co*CC + ci)*TT;
    #pragma unroll
    for (int tq = 0; tq < TT-1; ++tq) acc += base[tq*LL] * wv[tq];
    acc += pp[ci*LL + l] * wv[TT-1];
  }
  part[h][l] = acc;
  __syncthreads();
  if (h == 0) {
    float scale = bng[co] * 0.999995000037499687f;   // 1/sqrt(1+1e-5)
    sy[l] = fmaxf((part[0][l] + part[1][l]) * scale + bnb[co], 0.f);
  }
  __syncthreads();
  float accp = (h == 0) ? plb[l] : 0.f;
  #pragma unroll 4
  for (int lq = 0; lq < 256; ++lq) {
    int ll = h*256 + lq;
    accp += sy[ll] * plwT[ll*LL + l];
  }
  part[h][l] = accp;
  __syncthreads();
  if (h == 0)
    out[((b*CC + co)*TT + (TT-1))*LL + l] = xm8[bc*LL + l] - (part[0][l] + part[1][l]);
}

extern "C" void kernel_launch(void* const* d_in, const int* in_sizes, int n_in,
                              void* d_out, int out_size, void* d_ws, size_t ws_size,
                              hipStream_t stream) {
  const float* x    = (const float*)d_in[0];
  const float* Wq   = (const float*)d_in[1];
  const float* bq   = (const float*)d_in[2];
  const float* Wk   = (const float*)d_in[3];
  const float* bk   = (const float*)d_in[4];
  const float* Wv   = (const float*)d_in[5];
  const float* bv   = (const float*)d_in[6];
  const float* Wm   = (const float*)d_in[7];
  const float* bm   = (const float*)d_in[8];
  const float* Wl   = (const float*)d_in[9];
  const float* Wc   = (const float*)d_in[10];
  const float* rpb  = (const float*)d_in[11];
  const float* pp   = (const float*)d_in[12];
  const float* cw   = (const float*)d_in[13];
  const float* cb   = (const float*)d_in[14];
  const float* bng  = (const float*)d_in[15];
  const float* bnb  = (const float*)d_in[16];
  const float* plw  = (const float*)d_in[17];
  const float* plb  = (const float*)d_in[18];
  float* out = (float*)d_out;

  float* ws = (float*)d_ws;
  const size_t NE = (size_t)NBT*LL*CC;         // 1179648
  float* q_ws   = ws;                          // NE fp32 [bt][l][32]
  short* kb_ws  = (short*)(q_ws + NE);         // NE bf16 kb2[bt][2][512][16]
  short* vt_ws  = kb_ws + NE;                  // NE bf16 vt2[bt][32][32][16]
  float* xm8    = (float*)(vt_ws + NE);        // 131072
  float* plwT   = xm8 + (size_t)BB*CC*LL;      // 262144
  float* mbias  = plwT + (size_t)LL*LL;        // 8*1024

  pre_kernel<<<836, 256, 0, stream>>>(x, Wq, bq, Wk, bk, Wv, bv,
                                      q_ws, kb_ws, vt_ws,
                                      plw, plwT, rpb, Wl, mbias);
  attn_kernel<<<NBT*16, 256, 0, stream>>>(q_ws, kb_ws, vt_ws, Wl, Wc, mbias,
                                          Wm, bm, out, xm8);
  convpl_kernel<<<BB*CC, 1024, 0, stream>>>(out, pp, cw, cb, bng, bnb,
                                            plwT, plb, xm8, out);
}